// Round 8
// baseline (115.539 us; speedup 1.0000x reference)
//
#include <hip/hip_runtime.h>
#include <hip/hip_bf16.h>

typedef _Float16 f16;
typedef f16 f16x8 __attribute__((ext_vector_type(8)));
typedef f16 f16x4 __attribute__((ext_vector_type(4)));
typedef float f32x4 __attribute__((ext_vector_type(4)));

#define MFMA_F16(a, b, c) __builtin_amdgcn_mfma_f32_16x16x32_f16((a), (b), (c), 0, 0, 0)
#define LOG2E 1.44269504f

// ---------------------------------------------------------------------------
// async global->LDS 16B copy
// ---------------------------------------------------------------------------
__device__ __forceinline__ void ld_lds16(const void* g, void* l) {
  __builtin_amdgcn_global_load_lds((const __attribute__((address_space(1))) void*)g,
                                   (__attribute__((address_space(3))) void*)l, 16, 0, 0);
}

// ---------------------------------------------------------------------------
// cast fp32 -> fp16; wq additionally scaled by log2(e) so attention scores
// land in the exp2 domain (saves a v_mul per softmax element).
// ---------------------------------------------------------------------------
__global__ __launch_bounds__(256) void cast_all(
    const float* __restrict__ hs, const float* __restrict__ wq,
    const float* __restrict__ wk, const float* __restrict__ wv,
    const float* __restrict__ wo, f16* __restrict__ hb,
    f16* __restrict__ wqb, f16* __restrict__ wkb,
    f16* __restrict__ wvb, f16* __restrict__ wob) {
  int idx = blockIdx.x * 256 + threadIdx.x;  // 1,572,864 float4 chunks total
  const float* src;
  f16* dst;
  int j;
  float scale = 1.0f;
  if (idx < 524288) {  // hidden: 2M floats / 4
    src = hs; dst = hb; j = idx;
  } else {
    int t = idx - 524288;
    int w = t >> 18;      // 262144 float4 per weight
    j = t & 262143;
    src = (w == 0) ? wq : (w == 1) ? wk : (w == 2) ? wv : wo;
    dst = (w == 0) ? wqb : (w == 1) ? wkb : (w == 2) ? wvb : wob;
    if (w == 0) scale = LOG2E;
  }
  float4 v = ((const float4*)src)[j];
  f16x4 o;
  o[0] = (f16)(v.x * scale); o[1] = (f16)(v.y * scale);
  o[2] = (f16)(v.z * scale); o[3] = (f16)(v.w * scale);
  ((f16x4*)dst)[j] = o;
}

// ---------------------------------------------------------------------------
// relative-position bias table: btab[h][rel + 2047], rel = kv - q, PRE-SCALED
// by log2(e) (exp2-domain softmax).
// ---------------------------------------------------------------------------
__global__ __launch_bounds__(256) void build_bias(const float* __restrict__ rb,
                                                  float* __restrict__ btab) {
  int idx = blockIdx.x * 256 + threadIdx.x;  // 65536 = 16 heads * 4096
  int h = idx >> 12;
  int t = idx & 4095;
  int rel = t - 2047;
  int bucket = (rel > 0) ? 16 : 0;
  int a = (rel < 0) ? -rel : rel;
  int lg;
  if (a < 8) {
    lg = a;
  } else {
    int cnt = (a >= 12) + (a >= 16) + (a >= 23) + (a >= 32) + (a >= 46) +
              (a >= 64) + (a >= 91);
    lg = 8 + cnt;  // max 15
  }
  bucket += lg;
  btab[idx] = rb[bucket * 16 + h] * LOG2E;  // rel_bias[32][16]
}

// ---------------------------------------------------------------------------
// GEMM mainloop: C[64x128] tile of A[M,1024] * B[N,1024]^T (both row-major).
// ---------------------------------------------------------------------------
__device__ __forceinline__ void gemm_mainloop(const f16* __restrict__ A,
                                              const f16* __restrict__ B,
                                              int brow, int bcol,
                                              f16* lA, f16* lB,
                                              f32x4 acc[4][2]) {
  const int tid = threadIdx.x;
  const int lane = tid & 63;
  const int wn = tid >> 6;
  const int lo = lane & 15;
  const int hi = lane >> 4;
  const int sw = lo & 7;
  const int sr = tid >> 3;                       // 0..31
  const int se = (((tid & 7) ^ (sr & 7)) << 3);  // swizzled col elem offset
  const f16* gA = A + (size_t)(brow + sr) * 1024 + se;
  const f16* gB = B + (size_t)(bcol + sr) * 1024 + se;
  f16* laD = lA + tid * 8;
  f16* lbD = lB + tid * 8;
  for (int k0 = 0; k0 < 1024; k0 += 64) {
    ld_lds16(gA + k0,             laD);
    ld_lds16(gA + k0 + 32 * 1024, laD + 2048);
    ld_lds16(gB + k0,             lbD);
    ld_lds16(gB + k0 + 32 * 1024, lbD + 2048);
    ld_lds16(gB + k0 + 64 * 1024, lbD + 4096);
    ld_lds16(gB + k0 + 96 * 1024, lbD + 6144);
    __syncthreads();
    f16x8 af[4][2], bf[2][2];
#pragma unroll
    for (int m = 0; m < 4; ++m)
#pragma unroll
      for (int ks = 0; ks < 2; ++ks)
        af[m][ks] = *(const f16x8*)(lA + (m * 16 + lo) * 64 +
                                    (((ks << 2) | hi) ^ sw) * 8);
#pragma unroll
    for (int j = 0; j < 2; ++j)
#pragma unroll
      for (int ks = 0; ks < 2; ++ks)
        bf[j][ks] = *(const f16x8*)(lB + (wn * 32 + j * 16 + lo) * 64 +
                                    (((ks << 2) | hi) ^ sw) * 8);
#pragma unroll
    for (int m = 0; m < 4; ++m)
#pragma unroll
      for (int j = 0; j < 2; ++j)
#pragma unroll
        for (int ks = 0; ks < 2; ++ks)
          acc[m][j] = MFMA_F16(af[m][ks], bf[j][ks], acc[m][j]);
    __syncthreads();
  }
}

// QKV projections fused over blockIdx.z (0=Q, 1=K, 2=V-transposed)
__global__ __launch_bounds__(256) void gemm_qkv(
    const f16* __restrict__ A, const f16* __restrict__ Wq,
    const f16* __restrict__ Wk, const f16* __restrict__ Wv,
    f16* __restrict__ Qo, f16* __restrict__ Ko, f16* __restrict__ VTo) {
  __shared__ __align__(16) f16 lA[64 * 64];
  __shared__ __align__(16) f16 lB[128 * 64];
  const int z = blockIdx.z;
  const f16* B = (z == 0) ? Wq : (z == 1) ? Wk : Wv;
  const int brow = blockIdx.x * 64, bcol = blockIdx.y * 128;
  f32x4 acc[4][2];
#pragma unroll
  for (int m = 0; m < 4; ++m)
#pragma unroll
    for (int j = 0; j < 2; ++j) acc[m][j] = f32x4{0.f, 0.f, 0.f, 0.f};
  gemm_mainloop(A, B, brow, bcol, lA, lB, acc);
  const int lane = threadIdx.x & 63, wn = threadIdx.x >> 6;
  const int lo = lane & 15, hi = lane >> 4;
  if (z < 2) {
    f16* C = z ? Ko : Qo;
#pragma unroll
    for (int m = 0; m < 4; ++m)
#pragma unroll
      for (int j = 0; j < 2; ++j) {
        int col = bcol + wn * 32 + j * 16 + lo;
        int row0 = brow + m * 16 + hi * 4;
#pragma unroll
        for (int r = 0; r < 4; ++r)
          C[(size_t)(row0 + r) * 1024 + col] = (f16)acc[m][j][r];
      }
  } else {
    // V transposed: VT[n][s], n = h*64+dv
#pragma unroll
    for (int m = 0; m < 4; ++m)
#pragma unroll
      for (int j = 0; j < 2; ++j) {
        int col = bcol + wn * 32 + j * 16 + lo;   // n
        int row0 = brow + m * 16 + hi * 4;        // s
        f16x4 v4;
#pragma unroll
        for (int r = 0; r < 4; ++r) v4[r] = (f16)acc[m][j][r];
        *(f16x4*)(VTo + (size_t)col * 2048 + row0) = v4;
      }
  }
}

// output projection: AO[2048,1024] * Wo[1024,1024]^T -> fp32 d_out
__global__ __launch_bounds__(256) void gemm_out(const f16* __restrict__ A,
                                                const f16* __restrict__ W,
                                                float* __restrict__ C) {
  __shared__ __align__(16) f16 lA[64 * 64];
  __shared__ __align__(16) f16 lB[128 * 64];
  const int brow = blockIdx.x * 64, bcol = blockIdx.y * 128;
  f32x4 acc[4][2];
#pragma unroll
  for (int m = 0; m < 4; ++m)
#pragma unroll
    for (int j = 0; j < 2; ++j) acc[m][j] = f32x4{0.f, 0.f, 0.f, 0.f};
  gemm_mainloop(A, W, brow, bcol, lA, lB, acc);
  const int lane = threadIdx.x & 63, wn = threadIdx.x >> 6;
  const int lo = lane & 15, hi = lane >> 4;
#pragma unroll
  for (int m = 0; m < 4; ++m)
#pragma unroll
    for (int j = 0; j < 2; ++j) {
      int col = bcol + wn * 32 + j * 16 + lo;
      int row0 = brow + m * 16 + hi * 4;
#pragma unroll
      for (int r = 0; r < 4; ++r)
        C[(size_t)(row0 + r) * 1024 + col] = acc[m][j][r];
    }
}

// ---------------------------------------------------------------------------
// Flash attention v7: 32 q per wave (block = 128 q x 4 waves, grid 16x16).
// K/V fragments are read from LDS ONCE and reused for BOTH q-halves ->
// LDS traffic per unit work halved vs v4. 2-buffer staging + one
// __syncthreads per slot (r3-proven). Far-tile scalar bias (|rel|>=91
// saturates the T5 bucket). exp2-domain softmax (wq & btab pre-scaled).
// ---------------------------------------------------------------------------
__global__ __launch_bounds__(256) void attn_kernel(
    const f16* __restrict__ Q, const f16* __restrict__ K,
    const f16* __restrict__ VT, const float* __restrict__ btab,
    f16* __restrict__ AO) {
  __shared__ __align__(16) f16 lK[2][4096];
  __shared__ __align__(16) f16 lV[2][4096];
  __shared__ __align__(16) float biasL[2176];

  const int h = blockIdx.y;
  const int q0 = blockIdx.x * 128;
  const int tid = threadIdx.x;
  const int wave = tid >> 6, lane = tid & 63;
  const int lo = lane & 15, hi = lane >> 4;
  const int sw = lo & 7;
  const int qlo = q0 + wave * 32;
  // lane's two q rows: myq[qh] = qlo + qh*16 + lo
  const int myq0 = qlo + lo;
  const int myq1 = qlo + 16 + lo;

  const f16* Kh = K + h * 64;
  const f16* VTh = VT + (size_t)h * 64 * 2048;

  // Q fragments [qh][kk]
  f16x8 qf[2][2];
#pragma unroll
  for (int kk = 0; kk < 2; ++kk) {
    qf[0][kk] = *(const f16x8*)(Q + (size_t)myq0 * 1024 + h * 64 + kk * 32 + hi * 8);
    qf[1][kk] = *(const f16x8*)(Q + (size_t)myq1 * 1024 + h * 64 + kk * 32 + hi * 8);
  }
  // far-tile scalar biases (saturated buckets), already log2e-scaled
  const float bp = btab[h * 4096 + 4094];  // rel = +2047 -> bucket 31
  const float bn = btab[h * 4096 + 0];     // rel = -2047 -> bucket 15

  // bias window for this block's q-range: rel idx = kv + 127 + q0 - q
  {
    const float* bsrc = btab + h * 4096 + 1920 - q0;  // 2176 floats, 16B-aligned
    for (int c = tid; c < 544; c += 256)
      ld_lds16(bsrc + c * 4, biasL + c * 4);
  }
  // biasL index per lane: kvidx + bofs[qh]
  const int bofs0 = 127 - wave * 32 - lo;
  const int bofs1 = bofs0 - 16;

  // staging chunk indices (2 chunks each for K and V per thread)
  const int sc0 = wave * 64 + lane;
  const int sc1 = 256 + sc0;
  const int r0 = sc0 >> 3, e0 = (sc0 & 7) ^ (r0 & 7);
  const int r1 = sc1 >> 3, e1 = (sc1 & 7) ^ (r1 & 7);

#define STAGE(bufi, kv)                                                        \
  do {                                                                         \
    ld_lds16(Kh + (size_t)((kv) + r0) * 1024 + e0 * 8, &lK[bufi][sc0 * 8]);    \
    ld_lds16(Kh + (size_t)((kv) + r1) * 1024 + e1 * 8, &lK[bufi][sc1 * 8]);    \
    ld_lds16(VTh + (size_t)r0 * 2048 + (kv) + e0 * 8, &lV[bufi][sc0 * 8]);     \
    ld_lds16(VTh + (size_t)r1 * 2048 + (kv) + e1 * 8, &lV[bufi][sc1 * 8]);     \
  } while (0)

  float m_run[2] = {-1e30f, -1e30f}, l_run[2] = {0.f, 0.f};
  f32x4 oacc[4][2];
#pragma unroll
  for (int d = 0; d < 4; ++d)
#pragma unroll
    for (int qh = 0; qh < 2; ++qh) oacc[d][qh] = f32x4{0.f, 0.f, 0.f, 0.f};

  STAGE(0, 0);
  __syncthreads();

  for (int t = 0; t < 32; ++t) {
    const int kv0 = t * 64;
    const int b = t & 1;
    if (t < 31) STAGE(b ^ 1, kv0 + 64);

    const f16* lKb = lK[b];
    const f16* lVb = lV[b];

    // ---- K frags (shared across both q-halves) ----
    f16x8 kf[4][2];
#pragma unroll
    for (int m = 0; m < 4; ++m)
#pragma unroll
      for (int kk = 0; kk < 2; ++kk)
        kf[m][kk] = *(const f16x8*)&lKb[(m * 16 + lo) * 64 +
                                        (((kk << 2) | hi) ^ sw) * 8];
    // ---- V frags (shared across both q-halves) ----
    f16x8 vf[4][2];
#pragma unroll
    for (int d = 0; d < 4; ++d)
#pragma unroll
      for (int kk = 0; kk < 2; ++kk) {
        const int row = d * 16 + lo;
        const int cc = kk * 4 + (hi >> 1);
        const int ia = (hi & 1) * 4;
        f16x4 vlo = *(const f16x4*)&lVb[row * 64 + (cc ^ sw) * 8 + ia];
        f16x4 vhi = *(const f16x4*)&lVb[row * 64 + ((cc + 2) ^ sw) * 8 + ia];
#pragma unroll
        for (int r = 0; r < 4; ++r) { vf[d][kk][r] = vlo[r]; vf[d][kk][r + 4] = vhi[r]; }
      }

    // ---- bias: far tiles use a single scalar (bucket saturated) ----
    const int rmin = kv0 - (qlo + 31);
    const int rmax = kv0 + 63 - qlo;
    float bias[2][16];
    if (rmin >= 91 || rmax <= -91) {
      const float bf_ = (rmin >= 91) ? bp : bn;
#pragma unroll
      for (int qh = 0; qh < 2; ++qh)
#pragma unroll
        for (int i = 0; i < 16; ++i) bias[qh][i] = bf_;
    } else {
#pragma unroll
      for (int i = 0; i < 16; ++i) {
        const int kvi = kv0 + (i >> 2) * 16 + hi * 4 + (i & 3);
        bias[0][i] = biasL[kvi + bofs0];
        bias[1][i] = biasL[kvi + bofs1];
      }
    }

    // ---- QK^T ----
    f32x4 sacc[4][2];
    __builtin_amdgcn_s_setprio(1);
#pragma unroll
    for (int m = 0; m < 4; ++m)
#pragma unroll
      for (int qh = 0; qh < 2; ++qh) {
        sacc[m][qh] = f32x4{0.f, 0.f, 0.f, 0.f};
#pragma unroll
        for (int kk = 0; kk < 2; ++kk)
          sacc[m][qh] = MFMA_F16(kf[m][kk], qf[qh][kk], sacc[m][qh]);
      }
    __builtin_amdgcn_s_setprio(0);

    // ---- softmax (exp2 domain) + P pack, per q-half ----
    f16x8 pf[2][2];
#pragma unroll
    for (int qh = 0; qh < 2; ++qh) {
      float p[16];
      float mx = -1e30f;
#pragma unroll
      for (int i = 0; i < 16; ++i) {
        float s = sacc[i >> 2][qh][i & 3] + bias[qh][i];
        p[i] = s;
        mx = fmaxf(mx, s);
      }
      mx = fmaxf(mx, __shfl_xor(mx, 16, 64));
      mx = fmaxf(mx, __shfl_xor(mx, 32, 64));
      if (!__all(mx <= m_run[qh] + 11.5416f)) {  // defer-max, e^8 bound
        float mn = fmaxf(m_run[qh], mx);
        float sc = exp2f(m_run[qh] - mn);
        l_run[qh] *= sc;
#pragma unroll
        for (int d = 0; d < 4; ++d) oacc[d][qh] *= sc;
        m_run[qh] = mn;
      }
      float ps = 0.f;
#pragma unroll
      for (int i = 0; i < 16; ++i) {
        p[i] = exp2f(p[i] - m_run[qh]);
        ps += p[i];
      }
      ps += __shfl_xor(ps, 16, 64);
      ps += __shfl_xor(ps, 32, 64);
      l_run[qh] += ps;
#pragma unroll
      for (int kk = 0; kk < 2; ++kk)
#pragma unroll
        for (int j = 0; j < 8; ++j)
          pf[qh][kk][j] = (f16)p[(kk * 2 + (j >> 2)) * 4 + (j & 3)];
    }

    // ---- PV (vf reused for both q-halves) ----
    __builtin_amdgcn_s_setprio(1);
#pragma unroll
    for (int d = 0; d < 4; ++d)
#pragma unroll
      for (int qh = 0; qh < 2; ++qh)
#pragma unroll
        for (int kk = 0; kk < 2; ++kk)
          oacc[d][qh] = MFMA_F16(vf[d][kk], pf[qh][kk], oacc[d][qh]);
    __builtin_amdgcn_s_setprio(0);

    __syncthreads();
  }
#undef STAGE

  // ---- epilogue ----
#pragma unroll
  for (int qh = 0; qh < 2; ++qh) {
    const int myq = qh ? myq1 : myq0;
    float inv = 1.f / l_run[qh];
#pragma unroll
    for (int d = 0; d < 4; ++d) {
      f16x4 ov;
#pragma unroll
      for (int r = 0; r < 4; ++r) ov[r] = (f16)(oacc[d][qh][r] * inv);
      *(f16x4*)(AO + (size_t)myq * 1024 + h * 64 + d * 16 + hi * 4) = ov;
    }
  }
}

// ---------------------------------------------------------------------------
extern "C" void kernel_launch(void* const* d_in, const int* in_sizes, int n_in,
                              void* d_out, int out_size, void* d_ws, size_t ws_size,
                              hipStream_t stream) {
  const float* hs = (const float*)d_in[0];
  const float* wq = (const float*)d_in[1];
  const float* wk = (const float*)d_in[2];
  const float* wv = (const float*)d_in[3];
  const float* wo = (const float*)d_in[4];
  const float* rb = (const float*)d_in[5];

  char* w = (char*)d_ws;
  f16* hb  = (f16*)w; w += (size_t)2048 * 1024 * 2;
  f16* wqb = (f16*)w; w += (size_t)1024 * 1024 * 2;
  f16* wkb = (f16*)w; w += (size_t)1024 * 1024 * 2;
  f16* wvb = (f16*)w; w += (size_t)1024 * 1024 * 2;
  f16* wob = (f16*)w; w += (size_t)1024 * 1024 * 2;
  f16* Qb  = (f16*)w; w += (size_t)2048 * 1024 * 2;
  f16* Kb  = (f16*)w; w += (size_t)2048 * 1024 * 2;
  f16* VTb = (f16*)w; w += (size_t)2048 * 1024 * 2;
  f16* AOb = (f16*)w; w += (size_t)2048 * 1024 * 2;
  float* btab = (float*)w; w += (size_t)16 * 4096 * 4;

  cast_all<<<6144, 256, 0, stream>>>(hs, wq, wk, wv, wo, hb, wqb, wkb, wvb, wob);
  build_bias<<<256, 256, 0, stream>>>(rb, btab);
  gemm_qkv<<<dim3(32, 8, 3), 256, 0, stream>>>(hb, wqb, wkb, wvb, Qb, Kb, VTb);
  attn_kernel<<<dim3(16, 16), 256, 0, stream>>>(Qb, Kb, VTb, btab, AOb);
  gemm_out<<<dim3(32, 8), 256, 0, stream>>>(AOb, wob, (float*)d_out);
}

// Round 9
// 103.259 us; speedup vs baseline: 1.1189x; 1.1189x over previous
//
#include <hip/hip_runtime.h>
#include <hip/hip_bf16.h>

typedef _Float16 f16;
typedef f16 f16x8 __attribute__((ext_vector_type(8)));
typedef f16 f16x4 __attribute__((ext_vector_type(4)));
typedef float f32x4 __attribute__((ext_vector_type(4)));

#define MFMA_F16(a, b, c) __builtin_amdgcn_mfma_f32_16x16x32_f16((a), (b), (c), 0, 0, 0)
#define LOG2E 1.44269504f

// ---------------------------------------------------------------------------
// async global->LDS 16B copy
// ---------------------------------------------------------------------------
__device__ __forceinline__ void ld_lds16(const void* g, void* l) {
  __builtin_amdgcn_global_load_lds((const __attribute__((address_space(1))) void*)g,
                                   (__attribute__((address_space(3))) void*)l, 16, 0, 0);
}

// ---------------------------------------------------------------------------
// cast fp32 -> fp16; wq scaled by log2(e) (exp2-domain softmax)
// ---------------------------------------------------------------------------
__global__ __launch_bounds__(256) void cast_all(
    const float* __restrict__ hs, const float* __restrict__ wq,
    const float* __restrict__ wk, const float* __restrict__ wv,
    const float* __restrict__ wo, f16* __restrict__ hb,
    f16* __restrict__ wqb, f16* __restrict__ wkb,
    f16* __restrict__ wvb, f16* __restrict__ wob) {
  int idx = blockIdx.x * 256 + threadIdx.x;  // 1,572,864 float4 chunks total
  const float* src;
  f16* dst;
  int j;
  float scale = 1.0f;
  if (idx < 524288) {  // hidden: 2M floats / 4
    src = hs; dst = hb; j = idx;
  } else {
    int t = idx - 524288;
    int w = t >> 18;      // 262144 float4 per weight
    j = t & 262143;
    src = (w == 0) ? wq : (w == 1) ? wk : (w == 2) ? wv : wo;
    dst = (w == 0) ? wqb : (w == 1) ? wkb : (w == 2) ? wvb : wob;
    if (w == 0) scale = LOG2E;
  }
  float4 v = ((const float4*)src)[j];
  f16x4 o;
  o[0] = (f16)(v.x * scale); o[1] = (f16)(v.y * scale);
  o[2] = (f16)(v.z * scale); o[3] = (f16)(v.w * scale);
  ((f16x4*)dst)[j] = o;
}

// ---------------------------------------------------------------------------
// relative-position bias table: btab[h][rel + 2047], rel = kv - q, *log2(e)
// ---------------------------------------------------------------------------
__global__ __launch_bounds__(256) void build_bias(const float* __restrict__ rb,
                                                  float* __restrict__ btab) {
  int idx = blockIdx.x * 256 + threadIdx.x;  // 65536 = 16 heads * 4096
  int h = idx >> 12;
  int t = idx & 4095;
  int rel = t - 2047;
  int bucket = (rel > 0) ? 16 : 0;
  int a = (rel < 0) ? -rel : rel;
  int lg;
  if (a < 8) {
    lg = a;
  } else {
    int cnt = (a >= 12) + (a >= 16) + (a >= 23) + (a >= 32) + (a >= 46) +
              (a >= 64) + (a >= 91);
    lg = 8 + cnt;  // max 15
  }
  bucket += lg;
  btab[idx] = rb[bucket * 16 + h] * LOG2E;  // rel_bias[32][16]
}

// ---------------------------------------------------------------------------
// GEMM mainloop: C[64x128] tile of A[M,1024] * B[N,1024]^T (both row-major).
// ---------------------------------------------------------------------------
__device__ __forceinline__ void gemm_mainloop(const f16* __restrict__ A,
                                              const f16* __restrict__ B,
                                              int brow, int bcol,
                                              f16* lA, f16* lB,
                                              f32x4 acc[4][2]) {
  const int tid = threadIdx.x;
  const int lane = tid & 63;
  const int wn = tid >> 6;
  const int lo = lane & 15;
  const int hi = lane >> 4;
  const int sw = lo & 7;
  const int sr = tid >> 3;                       // 0..31
  const int se = (((tid & 7) ^ (sr & 7)) << 3);  // swizzled col elem offset
  const f16* gA = A + (size_t)(brow + sr) * 1024 + se;
  const f16* gB = B + (size_t)(bcol + sr) * 1024 + se;
  f16* laD = lA + tid * 8;
  f16* lbD = lB + tid * 8;
  for (int k0 = 0; k0 < 1024; k0 += 64) {
    ld_lds16(gA + k0,             laD);
    ld_lds16(gA + k0 + 32 * 1024, laD + 2048);
    ld_lds16(gB + k0,             lbD);
    ld_lds16(gB + k0 + 32 * 1024, lbD + 2048);
    ld_lds16(gB + k0 + 64 * 1024, lbD + 4096);
    ld_lds16(gB + k0 + 96 * 1024, lbD + 6144);
    __syncthreads();
    f16x8 af[4][2], bf[2][2];
#pragma unroll
    for (int m = 0; m < 4; ++m)
#pragma unroll
      for (int ks = 0; ks < 2; ++ks)
        af[m][ks] = *(const f16x8*)(lA + (m * 16 + lo) * 64 +
                                    (((ks << 2) | hi) ^ sw) * 8);
#pragma unroll
    for (int j = 0; j < 2; ++j)
#pragma unroll
      for (int ks = 0; ks < 2; ++ks)
        bf[j][ks] = *(const f16x8*)(lB + (wn * 32 + j * 16 + lo) * 64 +
                                    (((ks << 2) | hi) ^ sw) * 8);
#pragma unroll
    for (int m = 0; m < 4; ++m)
#pragma unroll
      for (int j = 0; j < 2; ++j)
#pragma unroll
        for (int ks = 0; ks < 2; ++ks)
          acc[m][j] = MFMA_F16(af[m][ks], bf[j][ks], acc[m][j]);
    __syncthreads();
  }
}

// QKV projections fused over blockIdx.z (0=Q, 1=K, 2=V-transposed+pi-permuted)
__global__ __launch_bounds__(256) void gemm_qkv(
    const f16* __restrict__ A, const f16* __restrict__ Wq,
    const f16* __restrict__ Wk, const f16* __restrict__ Wv,
    f16* __restrict__ Qo, f16* __restrict__ Ko, f16* __restrict__ VTo) {
  __shared__ __align__(16) f16 lA[64 * 64];
  __shared__ __align__(16) f16 lB[128 * 64];
  const int z = blockIdx.z;
  const f16* B = (z == 0) ? Wq : (z == 1) ? Wk : Wv;
  const int brow = blockIdx.x * 64, bcol = blockIdx.y * 128;
  f32x4 acc[4][2];
#pragma unroll
  for (int m = 0; m < 4; ++m)
#pragma unroll
    for (int j = 0; j < 2; ++j) acc[m][j] = f32x4{0.f, 0.f, 0.f, 0.f};
  gemm_mainloop(A, B, brow, bcol, lA, lB, acc);
  const int lane = threadIdx.x & 63, wn = threadIdx.x >> 6;
  const int lo = lane & 15, hi = lane >> 4;
  if (z < 2) {
    f16* C = z ? Ko : Qo;
#pragma unroll
    for (int m = 0; m < 4; ++m)
#pragma unroll
      for (int j = 0; j < 2; ++j) {
        int col = bcol + wn * 32 + j * 16 + lo;
        int row0 = brow + m * 16 + hi * 4;
#pragma unroll
        for (int r = 0; r < 4; ++r)
          C[(size_t)(row0 + r) * 1024 + col] = (f16)acc[m][j][r];
      }
  } else {
    // V transposed: VT[n][s'], n = h*64+dv.  s' applies pi within each 64-kv
    // tile: 4-elem group g = m*4+hi -> gp so that the PV fragment's two
    // 4-groups (w, w+4 within a 32-block) become one contiguous b128.
#pragma unroll
    for (int m = 0; m < 4; ++m)
#pragma unroll
      for (int j = 0; j < 2; ++j) {
        int col = bcol + wn * 32 + j * 16 + lo;   // n
        int g = m * 4 + hi;
        int w = g & 7;
        int gp = (g & 8) | ((w < 4) ? (2 * w) : (2 * (w - 4) + 1));
        int sp = brow + gp * 4;                   // permuted s
        f16x4 v4;
#pragma unroll
        for (int r = 0; r < 4; ++r) v4[r] = (f16)acc[m][j][r];
        *(f16x4*)(VTo + (size_t)col * 2048 + sp) = v4;
      }
  }
}

// output projection: AO[2048,1024] * Wo[1024,1024]^T -> fp32 d_out
__global__ __launch_bounds__(256) void gemm_out(const f16* __restrict__ A,
                                                const f16* __restrict__ W,
                                                float* __restrict__ C) {
  __shared__ __align__(16) f16 lA[64 * 64];
  __shared__ __align__(16) f16 lB[128 * 64];
  const int brow = blockIdx.x * 64, bcol = blockIdx.y * 128;
  f32x4 acc[4][2];
#pragma unroll
  for (int m = 0; m < 4; ++m)
#pragma unroll
    for (int j = 0; j < 2; ++j) acc[m][j] = f32x4{0.f, 0.f, 0.f, 0.f};
  gemm_mainloop(A, W, brow, bcol, lA, lB, acc);
  const int lane = threadIdx.x & 63, wn = threadIdx.x >> 6;
  const int lo = lane & 15, hi = lane >> 4;
#pragma unroll
  for (int m = 0; m < 4; ++m)
#pragma unroll
    for (int j = 0; j < 2; ++j) {
      int col = bcol + wn * 32 + j * 16 + lo;
      int row0 = brow + m * 16 + hi * 4;
#pragma unroll
      for (int r = 0; r < 4; ++r)
        C[(size_t)(row0 + r) * 1024 + col] = acc[m][j][r];
    }
}

// ---------------------------------------------------------------------------
// Flash attention v9: 32q/wave (K/V frags shared across 2 q-halves = half the
// LDS bytes per MAC) AND kv z-split (2 x 1024) to keep 512 blocks = 2/CU =
// 2 waves/SIMD. V is one b128 per fragment thanks to the pi-permuted VT
// layout. Far-tile scalar bias; exp2-domain softmax; defer-max.
// Partials (normalized O + m,l) merged exactly by merge_halves.
// ---------------------------------------------------------------------------
__global__ __launch_bounds__(256) void attn_kernel(
    const f16* __restrict__ Q, const f16* __restrict__ K,
    const f16* __restrict__ VT, const float* __restrict__ btab,
    f16* __restrict__ Oh, float2* __restrict__ Ml) {
  __shared__ __align__(16) f16 lK[2][4096];
  __shared__ __align__(16) f16 lV[2][4096];
  __shared__ __align__(16) float biasL[1152];

  const int h = blockIdx.y;
  const int q0 = blockIdx.x * 128;
  const int z = blockIdx.z;
  const int kvbase = z * 1024;
  const int tid = threadIdx.x;
  const int wave = tid >> 6, lane = tid & 63;
  const int lo = lane & 15, hi = lane >> 4;
  const int sw = lo & 7;
  const int qlo = q0 + wave * 32;
  const int myq0 = qlo + lo;
  const int myq1 = qlo + 16 + lo;

  const f16* Kh = K + h * 64;
  const f16* VTh = VT + (size_t)h * 64 * 2048;

  // Q fragments [qh][kk]
  f16x8 qf[2][2];
#pragma unroll
  for (int kk = 0; kk < 2; ++kk) {
    qf[0][kk] = *(const f16x8*)(Q + (size_t)myq0 * 1024 + h * 64 + kk * 32 + hi * 8);
    qf[1][kk] = *(const f16x8*)(Q + (size_t)myq1 * 1024 + h * 64 + kk * 32 + hi * 8);
  }
  // far-tile scalar biases (saturated buckets), log2e-scaled
  const float bp = btab[h * 4096 + 4094];  // rel >= +91 region (bucket 31)
  const float bn = btab[h * 4096 + 0];     // rel <= -91 region (bucket 15)

  // bias window: idx = (kv - kvbase) + 127 - (q - q0), range [0, 1151)
  {
    const float* bsrc = btab + h * 4096 + 1920 + kvbase - q0;
    for (int c = tid; c < 288; c += 256)
      ld_lds16(bsrc + c * 4, biasL + c * 4);
  }
  const int bofs0 = 127 - wave * 32 - lo;
  const int bofs1 = bofs0 - 16;

  // staging chunk indices (2 chunks each for K and V per thread)
  const int sc0 = wave * 64 + lane;
  const int sc1 = 256 + sc0;
  const int r0 = sc0 >> 3, e0 = (sc0 & 7) ^ (r0 & 7);
  const int r1 = sc1 >> 3, e1 = (sc1 & 7) ^ (r1 & 7);

#define STAGE(bufi, kv)                                                        \
  do {                                                                         \
    ld_lds16(Kh + (size_t)((kv) + r0) * 1024 + e0 * 8, &lK[bufi][sc0 * 8]);    \
    ld_lds16(Kh + (size_t)((kv) + r1) * 1024 + e1 * 8, &lK[bufi][sc1 * 8]);    \
    ld_lds16(VTh + (size_t)r0 * 2048 + (kv) + e0 * 8, &lV[bufi][sc0 * 8]);     \
    ld_lds16(VTh + (size_t)r1 * 2048 + (kv) + e1 * 8, &lV[bufi][sc1 * 8]);     \
  } while (0)

  float m_run[2] = {-1e30f, -1e30f}, l_run[2] = {0.f, 0.f};
  f32x4 oacc[4][2];
#pragma unroll
  for (int d = 0; d < 4; ++d)
#pragma unroll
    for (int qh = 0; qh < 2; ++qh) oacc[d][qh] = f32x4{0.f, 0.f, 0.f, 0.f};

  STAGE(0, kvbase);
  __syncthreads();

  for (int t = 0; t < 16; ++t) {
    const int kv0 = kvbase + t * 64;
    const int b = t & 1;
    if (t < 15) STAGE(b ^ 1, kv0 + 64);

    const f16* lKb = lK[b];
    const f16* lVb = lV[b];

    // ---- K frags (shared across both q-halves) ----
    f16x8 kf[4][2];
#pragma unroll
    for (int m = 0; m < 4; ++m)
#pragma unroll
      for (int kk = 0; kk < 2; ++kk)
        kf[m][kk] = *(const f16x8*)&lKb[(m * 16 + lo) * 64 +
                                        (((kk << 2) | hi) ^ sw) * 8];
    // ---- V frags: ONE b128 each (pi-permuted layout), shared across qh ----
    f16x8 vf[4][2];
#pragma unroll
    for (int d = 0; d < 4; ++d)
#pragma unroll
      for (int kk = 0; kk < 2; ++kk)
        vf[d][kk] = *(const f16x8*)&lVb[(d * 16 + lo) * 64 +
                                        ((kk * 4 + hi) ^ sw) * 8];

    // ---- QK^T ----
    f32x4 sacc[4][2];
    __builtin_amdgcn_s_setprio(1);
#pragma unroll
    for (int m = 0; m < 4; ++m)
#pragma unroll
      for (int qh = 0; qh < 2; ++qh) {
        sacc[m][qh] = f32x4{0.f, 0.f, 0.f, 0.f};
#pragma unroll
        for (int kk = 0; kk < 2; ++kk)
          sacc[m][qh] = MFMA_F16(kf[m][kk], qf[qh][kk], sacc[m][qh]);
      }
    __builtin_amdgcn_s_setprio(0);

    // ---- bias selection (wave-uniform branch) ----
    const int rmin = kv0 - (qlo + 31);
    const int rmax = kv0 + 63 - qlo;
    const bool far = (rmin >= 91) || (rmax <= -91);
    const float bfar = (rmin >= 91) ? bp : bn;
    const int kvl = kv0 - kvbase;

    // ---- softmax (exp2 domain) + P pack, per q-half ----
    f16x8 pf[2][2];
#pragma unroll
    for (int qh = 0; qh < 2; ++qh) {
      const int bofs = qh ? bofs1 : bofs0;
      float p[16];
      float mx = -1e30f;
#pragma unroll
      for (int i = 0; i < 16; ++i) {
        float bia = far ? bfar
                        : biasL[kvl + (i >> 2) * 16 + hi * 4 + (i & 3) + bofs];
        float s = sacc[i >> 2][qh][i & 3] + bia;
        p[i] = s;
        mx = fmaxf(mx, s);
      }
      mx = fmaxf(mx, __shfl_xor(mx, 16, 64));
      mx = fmaxf(mx, __shfl_xor(mx, 32, 64));
      if (!__all(mx <= m_run[qh] + 11.5416f)) {  // defer-max (e^8 in log2)
        float mn = fmaxf(m_run[qh], mx);
        float sc = exp2f(m_run[qh] - mn);
        l_run[qh] *= sc;
#pragma unroll
        for (int d = 0; d < 4; ++d) oacc[d][qh] *= sc;
        m_run[qh] = mn;
      }
      float ps = 0.f;
#pragma unroll
      for (int i = 0; i < 16; ++i) {
        p[i] = exp2f(p[i] - m_run[qh]);
        ps += p[i];
      }
      ps += __shfl_xor(ps, 16, 64);
      ps += __shfl_xor(ps, 32, 64);
      l_run[qh] += ps;
#pragma unroll
      for (int kk = 0; kk < 2; ++kk)
#pragma unroll
        for (int j = 0; j < 8; ++j)
          pf[qh][kk][j] = (f16)p[(kk * 2 + (j >> 2)) * 4 + (j & 3)];
    }

    // ---- PV (vf reused for both q-halves) ----
    __builtin_amdgcn_s_setprio(1);
#pragma unroll
    for (int d = 0; d < 4; ++d)
#pragma unroll
      for (int qh = 0; qh < 2; ++qh)
#pragma unroll
        for (int kk = 0; kk < 2; ++kk)
          oacc[d][qh] = MFMA_F16(vf[d][kk], pf[qh][kk], oacc[d][qh]);
    __builtin_amdgcn_s_setprio(0);

    __syncthreads();
  }
#undef STAGE

  // ---- epilogue: normalized partial O -> Oh[z], (m,l) -> Ml[z] ----
  f16* OhZ = Oh + (size_t)z * 2048 * 1024;
#pragma unroll
  for (int qh = 0; qh < 2; ++qh) {
    const int myq = qh ? myq1 : myq0;
    float inv = 1.f / l_run[qh];
#pragma unroll
    for (int d = 0; d < 4; ++d) {
      f16x4 ov;
#pragma unroll
      for (int r = 0; r < 4; ++r) ov[r] = (f16)(oacc[d][qh][r] * inv);
      *(f16x4*)(OhZ + (size_t)myq * 1024 + h * 64 + d * 16 + hi * 4) = ov;
    }
    if (hi == 0) Ml[(z * 16 + h) * 2048 + myq] = float2{m_run[qh], l_run[qh]};
  }
}

// ---------------------------------------------------------------------------
// exact merge of the two KV-half partials: AO = w0*Oh0 + w1*Oh1
// (m,l in exp2 domain; weights use exp2f)
// ---------------------------------------------------------------------------
__global__ __launch_bounds__(256) void merge_halves(
    const f16* __restrict__ Oh, const float2* __restrict__ Ml,
    f16* __restrict__ AO) {
  int idx = blockIdx.x * 256 + threadIdx.x;  // 262144 f16x8 chunks
  int q = idx >> 7;                          // 128 chunks per q-row
  int h = (idx & 127) >> 3;                  // 8 chunks per head
  float2 ml0 = Ml[h * 2048 + q];
  float2 ml1 = Ml[(16 + h) * 2048 + q];
  float M = fmaxf(ml0.x, ml1.x);
  float w0 = ml0.y * exp2f(ml0.x - M);
  float w1 = ml1.y * exp2f(ml1.x - M);
  float inv = 1.f / (w0 + w1);
  w0 *= inv;
  w1 *= inv;
  f16x8 a = ((const f16x8*)Oh)[idx];
  f16x8 b = ((const f16x8*)(Oh + (size_t)2048 * 1024))[idx];
  f16x8 o;
#pragma unroll
  for (int r = 0; r < 8; ++r)
    o[r] = (f16)(w0 * (float)a[r] + w1 * (float)b[r]);
  ((f16x8*)AO)[idx] = o;
}

// ---------------------------------------------------------------------------
extern "C" void kernel_launch(void* const* d_in, const int* in_sizes, int n_in,
                              void* d_out, int out_size, void* d_ws, size_t ws_size,
                              hipStream_t stream) {
  const float* hs = (const float*)d_in[0];
  const float* wq = (const float*)d_in[1];
  const float* wk = (const float*)d_in[2];
  const float* wv = (const float*)d_in[3];
  const float* wo = (const float*)d_in[4];
  const float* rb = (const float*)d_in[5];

  char* w = (char*)d_ws;
  f16* hb  = (f16*)w; w += (size_t)2048 * 1024 * 2;
  f16* wqb = (f16*)w; w += (size_t)1024 * 1024 * 2;
  f16* wkb = (f16*)w; w += (size_t)1024 * 1024 * 2;
  f16* wvb = (f16*)w; w += (size_t)1024 * 1024 * 2;
  f16* wob = (f16*)w; w += (size_t)1024 * 1024 * 2;
  f16* Qb  = (f16*)w; w += (size_t)2048 * 1024 * 2;
  f16* Kb  = (f16*)w; w += (size_t)2048 * 1024 * 2;
  f16* VTb = (f16*)w; w += (size_t)2048 * 1024 * 2;
  f16* AOb = (f16*)w; w += (size_t)2048 * 1024 * 2;
  float* btab = (float*)w; w += (size_t)16 * 4096 * 4;

  // partial buffers reuse hb/wqb/wkb (8 MB, dead after gemm_qkv) and wvb:
  f16* Oh = hb;                 // [2][2048][1024] f16 = 8 MB
  float2* Ml = (float2*)wvb;    // [2][16][2048] float2 = 512 KB

  cast_all<<<6144, 256, 0, stream>>>(hs, wq, wk, wv, wo, hb, wqb, wkb, wvb, wob);
  build_bias<<<256, 256, 0, stream>>>(rb, btab);
  gemm_qkv<<<dim3(32, 8, 3), 256, 0, stream>>>(hb, wqb, wkb, wvb, Qb, Kb, VTb);
  attn_kernel<<<dim3(16, 16, 2), 256, 0, stream>>>(Qb, Kb, VTb, btab, Oh, Ml);
  merge_halves<<<1024, 256, 0, stream>>>(Oh, Ml, AOb);
  gemm_out<<<dim3(32, 8), 256, 0, stream>>>(AOb, wob, (float*)d_out);
}